// Round 4
// baseline (586.214 us; speedup 1.0000x reference)
//
#include <hip/hip_runtime.h>

// Problem constants
#define NTOK 65536          // B*S = 16*4096 tokens
#define DDIM 64             // embedding dim
#define KCB  4096           // codebook size
#define MB   128            // tokens per block  (16 ty * 8 mt)
#define NB   128            // codes per tile    (16 tx * 8 nt, strided n = tx + 16c)
#define KS   68             // padded row stride in floats (64+4: 16B-aligned, +4 bank offset/row)
#define IDXOFF  (NTOK * DDIM)          // 4194304: indices start
#define LOSSOFF (NTOK * DDIM + NTOK)   // 4259840: scalar loss

// Empty asm barrier: keeps a rounded fp32 value opaque so the compiler cannot
// contract the preceding mul into a following add (must match numpy's
// round-square-then-add exactly).
__device__ __forceinline__ float opaque(float x) {
    asm volatile("" : "+v"(x));
    return x;
}

// numpy pairwise_sum for n=64 floats of squares:
// 8 accumulators r[j] over stride-8 lanes, ((r0+r1)+(r2+r3))+((r4+r5)+(r6+r7)).
__device__ __forceinline__ float np_sumsq64(const float* __restrict__ v) {
    float r[8];
#pragma unroll
    for (int j = 0; j < 8; ++j) r[j] = opaque(v[j] * v[j]);
#pragma unroll
    for (int i = 1; i < 8; ++i)
#pragma unroll
        for (int j = 0; j < 8; ++j) r[j] += opaque(v[8 * i + j] * v[8 * i + j]);
    return ((r[0] + r[1]) + (r[2] + r[3])) + ((r[4] + r[5]) + (r[6] + r[7]));
}

// ---------------- Kernel A: codebook squared norms + zero loss accum ----------------
__global__ void k_enorm(const float* __restrict__ emb, float* __restrict__ e2,
                        double* __restrict__ lossacc) {
    int k = blockIdx.x * blockDim.x + threadIdx.x;
    if (k == 0) *lossacc = 0.0;
    if (k < KCB) {
        float row[DDIM];
        const float4* r4 = (const float4*)(emb + (size_t)k * DDIM);
#pragma unroll
        for (int i = 0; i < DDIM / 4; ++i) {
            float4 v = r4[i];
            row[4*i+0] = v.x; row[4*i+1] = v.y; row[4*i+2] = v.z; row[4*i+3] = v.w;
        }
        e2[k] = np_sumsq64(row);
    }
}

// ---------------- Kernel B: LDS-tiled 8x8 register-blocked GEMM-argmin ----------------
// Grid: 512 blocks x 256 threads (tx = tid&15, ty = tid>>4).
// Natural [row][k] LDS layouts, stride KS=68 -> staging is a conflict-free
// float4 copy. Thread tile: m = ty*8+a (a<8), n = tx + 16*c (c<8).
// Each acc[a][c] is ONE sequential fmaf chain over k=0..63 (BLAS/np order):
//   s = fl( fl(z2 + e2_n) - m_n ),  m_n = seqFMA_k (2*z_k)*e_{n,k}
__global__ __launch_bounds__(256, 2) void k_vq(
    const float* __restrict__ z, const float* __restrict__ emb,
    const float* __restrict__ e2g, float* __restrict__ out,
    double* __restrict__ lossacc) {
    __shared__ float zs[MB * KS];     // 34.8 KB, holds 2*z; aliased later: bestv[m*17+tx]
    __shared__ float es[NB * KS];     // 34.8 KB; aliased later: besti[m*17+tx]
    __shared__ float z2s[MB];
    __shared__ float e2t[NB];
    __shared__ float red[256];
    __shared__ int   bidx_s[MB];

    const int tid = threadIdx.x;
    const int tx  = tid & 15;
    const int ty  = tid >> 4;
    const size_t zbase = (size_t)blockIdx.x * MB * DDIM;

    // ---- Stage z tile: straight float4 copy (conflict-free), doubled in place ----
#pragma unroll
    for (int it = 0; it < 8; ++it) {
        int f  = it * 256 + tid;        // 0..2047 float4 slots (128 tok * 16)
        int rr = f >> 4;                // token row
        int cc = f & 15;                // float4 chunk
        float4 v = ((const float4*)(z + zbase))[f];
        v.x += v.x; v.y += v.y; v.z += v.z; v.w += v.w;   // exact doubling
        ((float4*)(zs + rr * KS))[cc] = v;
    }
    // Prefetch e tile 0 into registers while zs settles.
    float4 pe[8];
    float  e2p = 0.f;
#pragma unroll
    for (int it = 0; it < 8; ++it) {
        int f  = it * 256 + tid;
        int rr = f >> 4;
        int cc = f & 15;
        pe[it] = ((const float4*)(emb + (size_t)rr * DDIM))[cc];
    }
    if (tid < NB) e2p = e2g[tid];
    __syncthreads();

    // ---- z2 per token: np pairwise of ORIGINAL z = 0.5*zs (exact halving) ----
    if (tid < MB) {
        const float* row = zs + tid * KS;
        float r8[8];
#pragma unroll
        for (int j = 0; j < 8; ++j) { float v = 0.5f * row[j]; r8[j] = opaque(v * v); }
#pragma unroll
        for (int i = 1; i < 8; ++i)
#pragma unroll
            for (int j = 0; j < 8; ++j) { float v = 0.5f * row[8*i+j]; r8[j] += opaque(v * v); }
        z2s[tid] = ((r8[0]+r8[1])+(r8[2]+r8[3])) + ((r8[4]+r8[5])+(r8[6]+r8[7]));
    }
    __syncthreads();

    float z2l[8];
#pragma unroll
    for (int a = 0; a < 8; ++a) z2l[a] = z2s[ty*8 + a];

    float best[8];
    int   bidx[8];
#pragma unroll
    for (int a = 0; a < 8; ++a) { best[a] = 3.0e38f; bidx[a] = 0; }

    for (int t = 0; t < KCB / NB; ++t) {
        const int n0 = t * NB;
        __syncthreads();   // previous tile's es reads complete before overwrite
        // ---- reg -> LDS (conflict-free copy) ----
#pragma unroll
        for (int it = 0; it < 8; ++it) {
            int f  = it * 256 + tid;
            int rr = f >> 4;
            int cc = f & 15;
            ((float4*)(es + rr * KS))[cc] = pe[it];
        }
        if (tid < NB) e2t[tid] = e2p;
        // ---- prefetch next tile to registers (hidden under this tile's math) ----
        if (t + 1 < KCB / NB) {
            const float* enext = emb + (size_t)(n0 + NB) * DDIM;
#pragma unroll
            for (int it = 0; it < 8; ++it) {
                int f  = it * 256 + tid;
                int rr = f >> 4;
                int cc = f & 15;
                pe[it] = ((const float4*)(enext + (size_t)rr * DDIM))[cc];
            }
            if (tid < NB) e2p = e2g[n0 + NB + tid];
        }
        __syncthreads();   // es ready

        // ---- 8x8 outer product; sequential k chains in np order ----
        float acc[8][8];
#pragma unroll
        for (int a = 0; a < 8; ++a)
#pragma unroll
            for (int c = 0; c < 8; ++c) acc[a][c] = 0.f;

#pragma unroll 4
        for (int kg = 0; kg < DDIM / 4; ++kg) {
            float za[8][4], ea[8][4];
#pragma unroll
            for (int a = 0; a < 8; ++a) {
                float4 v = *(const float4*)(zs + (ty*8 + a) * KS + kg*4);  // octet-broadcast
                za[a][0] = v.x; za[a][1] = v.y; za[a][2] = v.z; za[a][3] = v.w;
            }
#pragma unroll
            for (int c = 0; c < 8; ++c) {
                float4 v = *(const float4*)(es + (tx + 16*c) * KS + kg*4); // stride-68 lanes: conflict-free
                ea[c][0] = v.x; ea[c][1] = v.y; ea[c][2] = v.z; ea[c][3] = v.w;
            }
#pragma unroll
            for (int kk = 0; kk < 4; ++kk)
#pragma unroll
                for (int a = 0; a < 8; ++a)
#pragma unroll
                    for (int c = 0; c < 8; ++c)
                        acc[a][c] = fmaf(za[a][kk], ea[c][kk], acc[a][c]);
        }

        // ---- scores + running argmin (ascending c => ascending n; strict <) ----
#pragma unroll
        for (int c = 0; c < 8; ++c) {
            float e2v = e2t[tx + 16*c];
            int   n   = n0 + tx + 16*c;
#pragma unroll
            for (int a = 0; a < 8; ++a) {
                float s = (z2l[a] + e2v) - acc[a][c];   // two fp32 roundings, as np
                if (s < best[a]) { best[a] = s; bidx[a] = n; }
            }
        }
    }
    __syncthreads();   // all zs/es reads done; safe to alias

    // ---- Cross-thread combine: lexicographic (val, idx) per token ----
    float* bestv_s = zs;            // [m*17 + tx], 128*17 = 2176 floats
    int*   besti_s = (int*)es;
#pragma unroll
    for (int a = 0; a < 8; ++a) {
        int m = ty*8 + a;
        bestv_s[m*17 + tx] = best[a];
        besti_s[m*17 + tx] = bidx[a];
    }
    __syncthreads();
    if (tid < MB) {
        float b  = bestv_s[tid*17 + 0];
        int   bi = besti_s[tid*17 + 0];
#pragma unroll
        for (int x = 1; x < 16; ++x) {
            float v = bestv_s[tid*17 + x];
            int   i = besti_s[tid*17 + x];
            if (v < b || (v == b && i < bi)) { b = v; bi = i; }
        }
        bidx_s[tid] = bi;
        out[IDXOFF + blockIdx.x * MB + tid] = (float)bi;  // d_out read as fp32
    }
    __syncthreads();

    // ---- Epilogue: quantized gather-write (coalesced float4) + loss ----
    float lsum = 0.f;
#pragma unroll
    for (int it = 0; it < 8; ++it) {
        int f  = it * 256 + tid;    // 0..2047 float4 slots
        int tt = f >> 4;
        int cc = f & 15;
        int idx = bidx_s[tt];
        float4 qv = ((const float4*)(emb + (size_t)idx * DDIM))[cc];
        float4 zv = ((const float4*)(z + zbase))[f];
        ((float4*)(out + zbase))[f] = qv;
        float dx = qv.x - zv.x, dy = qv.y - zv.y;
        float dz = qv.z - zv.z, dw = qv.w - zv.w;
        lsum += dx * dx + dy * dy + dz * dz + dw * dw;
    }
    red[tid] = lsum;
    __syncthreads();
    for (int s = 128; s > 0; s >>= 1) {
        if (tid < s) red[tid] += red[tid + s];
        __syncthreads();
    }
    if (tid == 0) atomicAdd(lossacc, (double)red[0]);
}

// ---------------- Kernel C: finalize loss ----------------
__global__ void k_fin(const double* __restrict__ lossacc, float* __restrict__ out) {
    // vq_loss = e_latent + q_latent = 2 * mean((q - z)^2)
    out[LOSSOFF] = (float)(2.0 * (*lossacc) / (double)(NTOK * DDIM));
}

extern "C" void kernel_launch(void* const* d_in, const int* in_sizes, int n_in,
                              void* d_out, int out_size, void* d_ws, size_t ws_size,
                              hipStream_t stream) {
    const float* z   = (const float*)d_in[0];   // [16,4096,64] fp32
    const float* emb = (const float*)d_in[1];   // [4096,64] fp32
    float* out = (float*)d_out;
    float*  e2      = (float*)d_ws;                      // 4096 floats
    double* lossacc = (double*)((char*)d_ws + 16384);    // 8 bytes, aligned

    hipLaunchKernelGGL(k_enorm, dim3(16), dim3(256), 0, stream, emb, e2, lossacc);
    hipLaunchKernelGGL(k_vq, dim3(NTOK / MB), dim3(256), 0, stream,
                       z, emb, e2, out, lossacc);
    hipLaunchKernelGGL(k_fin, dim3(1), dim3(1), 0, stream, lossacc, out);
}

// Round 5
// 455.647 us; speedup vs baseline: 1.2866x; 1.2866x over previous
//
#include <hip/hip_runtime.h>

// Problem constants
#define NTOK 65536          // B*S tokens
#define DDIM 64             // embedding dim
#define KCB  4096           // codebook size
#define MB   128            // tokens per block
#define NCH  256            // codes per staged chunk
#define NCHUNKS (KCB / NCH) // 16
#define ESTR 72             // padded LDS row stride (bf16 elems): 16B-aligned, conflict-free frags
#define LCAP 6144           // candidate list capacity
#define WWIN 6.0e-5f        // rescore window: >= 2*(ulp(<256) + eps_mfma)
#define IDXOFF  (NTOK * DDIM)
#define LOSSOFF (NTOK * DDIM + NTOK)

typedef __bf16 bf16x8 __attribute__((ext_vector_type(8)));
typedef float  f32x4  __attribute__((ext_vector_type(4)));

// Keeps a rounded fp32 value opaque (blocks mul+add contraction) — np emulation.
__device__ __forceinline__ float opaque(float x) { asm volatile("" : "+v"(x)); return x; }

// numpy pairwise sum of squares, n=64: 8 stride-8 accs, ((r0+r1)+(r2+r3))+((r4+r5)+(r6+r7))
__device__ __forceinline__ float np_sumsq64(const float* __restrict__ v) {
    float r[8];
#pragma unroll
    for (int j = 0; j < 8; ++j) r[j] = opaque(v[j] * v[j]);
#pragma unroll
    for (int i = 1; i < 8; ++i)
#pragma unroll
        for (int j = 0; j < 8; ++j) r[j] += opaque(v[8 * i + j] * v[8 * i + j]);
    return ((r[0] + r[1]) + (r[2] + r[3])) + ((r[4] + r[5]) + (r[6] + r[7]));
}

__device__ __forceinline__ unsigned short bf16rne(float x) {
    unsigned u = __float_as_uint(x);
    return (unsigned short)((u + 0x7fffu + ((u >> 16) & 1u)) >> 16);
}
__device__ __forceinline__ float bf16tof(unsigned short h) {
    return __uint_as_float(((unsigned)h) << 16);
}

// ---- Prep: e2 (np pairwise) + split-bf16 codebook (e = eh + el), zero loss ----
__global__ void k_prep(const float* __restrict__ emb, float* __restrict__ e2,
                       unsigned short* __restrict__ eh, unsigned short* __restrict__ el,
                       double* __restrict__ lossacc) {
    int k = blockIdx.x * blockDim.x + threadIdx.x;
    if (k == 0) *lossacc = 0.0;
    if (k >= KCB) return;
    float row[DDIM];
    const float4* r4 = (const float4*)(emb + (size_t)k * DDIM);
#pragma unroll
    for (int i = 0; i < DDIM / 4; ++i) {
        float4 v = r4[i];
        row[4*i+0] = v.x; row[4*i+1] = v.y; row[4*i+2] = v.z; row[4*i+3] = v.w;
    }
    e2[k] = np_sumsq64(row);
#pragma unroll
    for (int j = 0; j < DDIM; ++j) {
        unsigned short h = bf16rne(row[j]);
        unsigned short l = bf16rne(row[j] - bf16tof(h));
        eh[(size_t)k * DDIM + j] = h;
        el[(size_t)k * DDIM + j] = l;
    }
}

// ---- Main: two MFMA sweeps + exact rescore of near-ties ----
// 512 threads = 8 waves (wm=w>>2 in {0,1}: 64 tokens; wn=w&3: 64-code column).
// m~ = (2z)@e^T via 3 bf16-split MFMA products; shat = fl(fl(z2+e2)-m~).
// Sweep 0: per-token min(shat) -> v0. Sweep 1: append (m,n) with shat<=v0+W.
// Rescore: exact np chain s=fl(fl(z2+e2)-seqFMA(2z*e)), lex-min (s,n) per token.
__global__ __launch_bounds__(512, 1) void k_vq(
    const float* __restrict__ z, const float* __restrict__ emb,
    const float* __restrict__ e2g,
    const unsigned short* __restrict__ ehg, const unsigned short* __restrict__ elg,
    float* __restrict__ out, double* __restrict__ lossacc) {
    __shared__ unsigned short zsh[MB * ESTR], zsl[MB * ESTR];   // split bf16 of 2*z
    __shared__ unsigned short esh[NCH * ESTR], esl[NCH * ESTR]; // split bf16 of e chunk
    __shared__ float z2s[MB];
    __shared__ float e2t[NCH];
    __shared__ unsigned v0u[MB];
    __shared__ unsigned long long keys[MB];
    __shared__ int list[LCAP];
    __shared__ int lcnt;
    __shared__ float red[512];
    __shared__ int bidx_s[MB];

    const int tid  = threadIdx.x;
    const int lane = tid & 63;
    const int l15  = lane & 15;
    const int quad = lane >> 4;
    const int w    = tid >> 6;
    const int wm   = w >> 2;    // 0..1
    const int wn   = w & 3;     // 0..3
    const size_t zbase = (size_t)blockIdx.x * MB * DDIM;

    if (tid < MB) { v0u[tid] = 0x7f800000u; keys[tid] = 0xFFFFFFFFFFFFFFFFull; }
    if (tid == 0) lcnt = 0;

    // ---- Stage z: fp32 global -> doubled split-bf16 LDS [m][k], stride ESTR ----
#pragma unroll
    for (int it = 0; it < 4; ++it) {
        int f  = it * 512 + tid;    // 0..2047 float4 slots
        int rr = f >> 4, c4 = f & 15;
        float4 v = ((const float4*)(z + zbase))[f];
        float d[4] = {v.x + v.x, v.y + v.y, v.z + v.z, v.w + v.w};  // exact 2*z
        ushort4 hh, ll;
        unsigned short h;
        h = bf16rne(d[0]); hh.x = h; ll.x = bf16rne(d[0] - bf16tof(h));
        h = bf16rne(d[1]); hh.y = h; ll.y = bf16rne(d[1] - bf16tof(h));
        h = bf16rne(d[2]); hh.z = h; ll.z = bf16rne(d[2] - bf16tof(h));
        h = bf16rne(d[3]); hh.w = h; ll.w = bf16rne(d[3] - bf16tof(h));
        *(ushort4*)(zsh + rr * ESTR + c4 * 4) = hh;
        *(ushort4*)(zsl + rr * ESTR + c4 * 4) = ll;
    }
    // z2 per token: np pairwise of original z (exact, as verified in R1)
    if (tid < MB) {
        float row[DDIM];
        const float4* zr4 = (const float4*)(z + zbase + (size_t)tid * DDIM);
#pragma unroll
        for (int i = 0; i < DDIM / 4; ++i) {
            float4 v = zr4[i];
            row[4*i+0] = v.x; row[4*i+1] = v.y; row[4*i+2] = v.z; row[4*i+3] = v.w;
        }
        z2s[tid] = np_sumsq64(row);
    }

    float vrun[16];
#pragma unroll
    for (int i = 0; i < 16; ++i) vrun[i] = 3.0e38f;

#pragma unroll 1
    for (int phase = 0; phase < 2; ++phase) {
#pragma unroll 1
        for (int ch = 0; ch < NCHUNKS; ++ch) {
            const int n0 = ch * NCH;
            __syncthreads();   // prior chunk frag reads done (also covers z staging)
            // ---- stage e chunk (split bf16, conflict-free copies) ----
#pragma unroll
            for (int it = 0; it < 8; ++it) {
                int f  = it * 512 + tid;    // 0..4095 ushort4 slots (256 rows * 16)
                int rr = f >> 4, c4 = f & 15;
                *(ushort4*)(esh + rr * ESTR + c4 * 4) =
                    ((const ushort4*)(ehg + (size_t)(n0 + rr) * DDIM))[c4];
                *(ushort4*)(esl + rr * ESTR + c4 * 4) =
                    ((const ushort4*)(elg + (size_t)(n0 + rr) * DDIM))[c4];
            }
            if (tid < NCH) e2t[tid] = e2g[n0 + tid];
            __syncthreads();

            // ---- hoisted B-fragments (e side): 4 nsub x {h k0,h k1,l k0,l k1} ----
            bf16x8 Bh0[4], Bh1[4], Bl0[4], Bl1[4];
#pragma unroll
            for (int ns = 0; ns < 4; ++ns) {
                int nl = wn * 64 + ns * 16 + l15;
                const unsigned short* pb = esh + nl * ESTR + quad * 8;
                const unsigned short* pc = esl + nl * ESTR + quad * 8;
                Bh0[ns] = *(const bf16x8*)(pb);
                Bh1[ns] = *(const bf16x8*)(pb + 32);
                Bl0[ns] = *(const bf16x8*)(pc);
                Bl1[ns] = *(const bf16x8*)(pc + 32);
            }
#pragma unroll
            for (int ms = 0; ms < 4; ++ms) {
                int ml = wm * 64 + ms * 16 + l15;
                const unsigned short* pa = zsh + ml * ESTR + quad * 8;
                const unsigned short* pq = zsl + ml * ESTR + quad * 8;
                bf16x8 Ah0 = *(const bf16x8*)(pa);
                bf16x8 Ah1 = *(const bf16x8*)(pa + 32);
                bf16x8 Al0 = *(const bf16x8*)(pq);
                bf16x8 Al1 = *(const bf16x8*)(pq + 32);
                f32x4 z2v = *(const f32x4*)(z2s + wm * 64 + ms * 16 + quad * 4);
                float vl[4];
                if (phase == 1) {
                    const unsigned* pv = v0u + wm * 64 + ms * 16 + quad * 4;
#pragma unroll
                    for (int r = 0; r < 4; ++r) vl[r] = __uint_as_float(pv[r]) + WWIN;
                }
#pragma unroll
                for (int ns = 0; ns < 4; ++ns) {
                    f32x4 acc = {0.f, 0.f, 0.f, 0.f};
                    acc = __builtin_amdgcn_mfma_f32_16x16x32_bf16(Ah0, Bh0[ns], acc, 0, 0, 0);
                    acc = __builtin_amdgcn_mfma_f32_16x16x32_bf16(Ah1, Bh1[ns], acc, 0, 0, 0);
                    acc = __builtin_amdgcn_mfma_f32_16x16x32_bf16(Ah0, Bl0[ns], acc, 0, 0, 0);
                    acc = __builtin_amdgcn_mfma_f32_16x16x32_bf16(Ah1, Bl1[ns], acc, 0, 0, 0);
                    acc = __builtin_amdgcn_mfma_f32_16x16x32_bf16(Al0, Bh0[ns], acc, 0, 0, 0);
                    acc = __builtin_amdgcn_mfma_f32_16x16x32_bf16(Al1, Bh1[ns], acc, 0, 0, 0);
                    int n = n0 + wn * 64 + ns * 16 + l15;
                    float e2v = e2t[wn * 64 + ns * 16 + l15];
#pragma unroll
                    for (int r = 0; r < 4; ++r) {
                        float shat = (z2v[r] + e2v) - acc[r];
                        if (phase == 0) {
                            vrun[ms * 4 + r] = fminf(vrun[ms * 4 + r], shat);
                        } else if (shat <= vl[r]) {
                            int m = wm * 64 + ms * 16 + quad * 4 + r;
                            int idx = atomicAdd(&lcnt, 1);
                            if (idx < LCAP) list[idx] = (m << 16) | n;
                        }
                    }
                }
            }
        }
        if (phase == 0) {
            // commit per-token mins: reduce across the 16 n-lanes, then LDS atomicMin
#pragma unroll
            for (int vi = 0; vi < 16; ++vi) {
                float v = vrun[vi];
                v = fminf(v, __shfl_xor(v, 1));
                v = fminf(v, __shfl_xor(v, 2));
                v = fminf(v, __shfl_xor(v, 4));
                v = fminf(v, __shfl_xor(v, 8));
                if (l15 == 0) {
                    int m = wm * 64 + (vi >> 2) * 16 + quad * 4 + (vi & 3);
                    atomicMin(&v0u[m], __float_as_uint(v));
                }
            }
            __syncthreads();
        }
    }
    __syncthreads();   // all appends visible

    // ---- Exact rescore of candidates: np chain, lexicographic (s, n) min ----
    int cnt = lcnt; if (cnt > LCAP) cnt = LCAP;
    for (int i = tid; i < cnt; i += 512) {
        int mn = list[i];
        int m = mn >> 16, n = mn & 0xffff;
        const float* zrow = z + zbase + (size_t)m * DDIM;
        const float* erow = emb + (size_t)n * DDIM;
        float a = 0.f;
#pragma unroll
        for (int j = 0; j < DDIM; ++j) a = fmaf(zrow[j] + zrow[j], erow[j], a);
        float s = (z2s[m] + e2g[n]) - a;   // two fp32 roundings, exactly as np
        unsigned long long key = ((unsigned long long)__float_as_uint(s) << 32)
                               | (unsigned long long)(unsigned)n;
        atomicMin(&keys[m], key);
    }
    __syncthreads();

    if (tid < MB) {
        int nstar = (int)(keys[tid] & 0xffffffffULL);
        bidx_s[tid] = nstar;
        out[IDXOFF + blockIdx.x * MB + tid] = (float)nstar;
    }
    __syncthreads();

    // ---- Epilogue: quantized gather-write (coalesced float4) + loss ----
    float lsum = 0.f;
#pragma unroll
    for (int it = 0; it < 4; ++it) {
        int f  = it * 512 + tid;    // 0..2047 float4 slots
        int tt = f >> 4, cc = f & 15;
        int idx = bidx_s[tt];
        float4 qv = ((const float4*)(emb + (size_t)idx * DDIM))[cc];
        float4 zv = ((const float4*)(z + zbase))[f];
        ((float4*)(out + zbase))[f] = qv;
        float dx = qv.x - zv.x, dy = qv.y - zv.y;
        float dz = qv.z - zv.z, dw = qv.w - zv.w;
        lsum += dx * dx + dy * dy + dz * dz + dw * dw;
    }
    red[tid] = lsum;
    __syncthreads();
    for (int s = 256; s > 0; s >>= 1) {
        if (tid < s) red[tid] += red[tid + s];
        __syncthreads();
    }
    if (tid == 0) atomicAdd(lossacc, (double)red[0]);
}

// ---- Finalize loss ----
__global__ void k_fin(const double* __restrict__ lossacc, float* __restrict__ out) {
    out[LOSSOFF] = (float)(2.0 * (*lossacc) / (double)(NTOK * DDIM));
}

extern "C" void kernel_launch(void* const* d_in, const int* in_sizes, int n_in,
                              void* d_out, int out_size, void* d_ws, size_t ws_size,
                              hipStream_t stream) {
    const float* z   = (const float*)d_in[0];   // [16,4096,64] fp32
    const float* emb = (const float*)d_in[1];   // [4096,64] fp32
    float* out = (float*)d_out;

    float*          e2g = (float*)d_ws;                                   // 16 KB
    unsigned short* ehg = (unsigned short*)((char*)d_ws + 16384);         // 512 KB
    unsigned short* elg = (unsigned short*)((char*)d_ws + 16384 + 524288);// 512 KB
    double* lossacc = (double*)((char*)d_ws + 16384 + 2 * 524288);

    hipLaunchKernelGGL(k_prep, dim3(16), dim3(256), 0, stream, emb, e2g, ehg, elg, lossacc);
    hipLaunchKernelGGL(k_vq, dim3(NTOK / MB), dim3(512), 0, stream,
                       z, emb, e2g, ehg, elg, out, lossacc);
    hipLaunchKernelGGL(k_fin, dim3(1), dim3(1), 0, stream, lossacc, out);
}